// Round 2
// baseline (9418.015 us; speedup 1.0000x reference)
//
#include <hip/hip_runtime.h>
#include <math.h>

#define N_NODES 100000
#define N_EDGES 3200000
#define F_IN    512
#define H1      16
#define H2      40

// ---------------------------------------------------------------------------
// Detect edge_index dtype: int64 (JAX x64 on) vs int32 (default).
// If int64: odd int32 words (high halves of values < 2^31) are all zero.
__global__ void detect_idx_kernel(const int* __restrict__ ei, int* __restrict__ flag)
{
    if (threadIdx.x == 0 && blockIdx.x == 0) {
        int all_zero = 1;
        for (int i = 0; i < 64; ++i)
            if (ei[2 * i + 1] != 0) { all_zero = 0; break; }
        *flag = all_zero;  // 1 => int64 layout, 0 => int32 layout
    }
}

__device__ __forceinline__ int edge_src(const void* ei, int e, int is64)
{
    return is64 ? (int)((const long long*)ei)[e] : ((const int*)ei)[e];
}
__device__ __forceinline__ int edge_dst(const void* ei, int e, int is64)
{
    return is64 ? (int)((const long long*)ei)[N_EDGES + e]
                : ((const int*)ei)[N_EDGES + e];
}

// ---------------------------------------------------------------------------
// deg[i] counts incoming edges (self-loop added later as +1.0f in rsqrt)
__global__ __launch_bounds__(256) void count_deg_kernel(
    const void* __restrict__ ei, const int* __restrict__ flag,
    float* __restrict__ deg, int n)
{
    const int is64 = *flag;
    int e = blockIdx.x * blockDim.x + threadIdx.x;
    if (e >= n) return;
    atomicAdd(&deg[edge_dst(ei, e, is64)], 1.0f);
}

// ---------------------------------------------------------------------------
// hs1[r][j] = (x[r] @ W1)[j] * dis[r];  dis[r] = rsqrt(deg[r]+1)
// Wave per row-pair; W1^T staged in LDS [16][512]; lane l covers k = l+64i.
__global__ __launch_bounds__(256) void gemm1_kernel(
    const float* __restrict__ x, const float* __restrict__ W1,
    const float* __restrict__ deg, float* __restrict__ hs1,
    float* __restrict__ dis, int n)
{
    __shared__ float w[16][512];
    for (int idx = threadIdx.x; idx < F_IN * H1; idx += 256) {
        int k = idx >> 4, j = idx & 15;
        w[j][k] = W1[idx];
    }
    __syncthreads();

    const int lane = threadIdx.x & 63;
    const int wid  = (blockIdx.x * blockDim.x + threadIdx.x) >> 6;
    const int nw   = (gridDim.x * blockDim.x) >> 6;

    for (int r0 = wid * 2; r0 < n; r0 += nw * 2) {
        const int r1 = r0 + 1;
        const float* xa = x + (size_t)r0 * F_IN;
        const float* xb = x + (size_t)r1 * F_IN;
        float acca[16], accb[16];
        #pragma unroll
        for (int j = 0; j < 16; ++j) { acca[j] = 0.f; accb[j] = 0.f; }
        #pragma unroll
        for (int i = 0; i < 8; ++i) {
            const int k = lane + 64 * i;
            const float xva = xa[k];
            const float xvb = xb[k];
            #pragma unroll
            for (int j = 0; j < 16; ++j) {
                const float wv = w[j][k];
                acca[j] += xva * wv;
                accb[j] += xvb * wv;
            }
        }
        #pragma unroll
        for (int off = 32; off > 0; off >>= 1) {
            #pragma unroll
            for (int j = 0; j < 16; ++j) {
                acca[j] += __shfl_xor(acca[j], off, 64);
                accb[j] += __shfl_xor(accb[j], off, 64);
            }
        }
        const float da = rsqrtf(deg[r0] + 1.0f);
        const float db = rsqrtf(deg[r1] + 1.0f);
        if (lane == 0) { dis[r0] = da; dis[r1] = db; }
        if (lane < 16) {
            hs1[(size_t)r0 * H1 + lane] = acca[lane] * da;
            hs1[(size_t)r1 * H1 + lane] = accb[lane] * db;
        }
    }
}

// ---------------------------------------------------------------------------
__global__ __launch_bounds__(256) void scatter1_kernel(
    const void* __restrict__ ei, const int* __restrict__ flag,
    const float* __restrict__ hs1, float* __restrict__ agg1, int n)
{
    const int is64 = *flag;
    int e = blockIdx.x * blockDim.x + threadIdx.x;
    if (e >= n) return;
    const int s = edge_src(ei, e, is64);
    const int d = edge_dst(ei, e, is64);
    const float4* hp = (const float4*)(hs1 + (size_t)s * H1);
    float* o = agg1 + (size_t)d * H1;
    #pragma unroll
    for (int q = 0; q < 4; ++q) {
        float4 v = hp[q];
        atomicAdd(o + 4 * q + 0, v.x);
        atomicAdd(o + 4 * q + 1, v.y);
        atomicAdd(o + 4 * q + 2, v.z);
        atomicAdd(o + 4 * q + 3, v.w);
    }
}

// ---------------------------------------------------------------------------
// a1 = relu(dis*(agg1 + hs1) + b1);  hs2 = (a1 @ W2) * dis   (b2 added later)
__global__ __launch_bounds__(256) void l1fin_gemm2_kernel(
    const float* __restrict__ agg1, const float* __restrict__ hs1,
    const float* __restrict__ b1, const float* __restrict__ W2,
    const float* __restrict__ dis, float* __restrict__ hs2, int n)
{
    __shared__ float w[H1 * H2];
    __shared__ float bb[H1];
    for (int t = threadIdx.x; t < H1 * H2; t += 256) w[t] = W2[t];
    if (threadIdx.x < H1) bb[threadIdx.x] = b1[threadIdx.x];
    __syncthreads();

    const int i = blockIdx.x * blockDim.x + threadIdx.x;
    if (i >= n) return;
    const float dv = dis[i];
    float a[16];
    #pragma unroll
    for (int k = 0; k < 16; ++k) {
        float t = dv * (agg1[(size_t)i * H1 + k] + hs1[(size_t)i * H1 + k]) + bb[k];
        a[k] = fmaxf(t, 0.f);
    }
    #pragma unroll
    for (int j = 0; j < H2; ++j) {
        float s = 0.f;
        #pragma unroll
        for (int k = 0; k < 16; ++k) s += a[k] * w[k * H2 + j];
        hs2[(size_t)i * H2 + j] = s * dv;
    }
}

// ---------------------------------------------------------------------------
__global__ __launch_bounds__(256) void scatter2_kernel(
    const void* __restrict__ ei, const int* __restrict__ flag,
    const float* __restrict__ hs2, float* __restrict__ agg2, int n)
{
    const int is64 = *flag;
    int e = blockIdx.x * blockDim.x + threadIdx.x;
    if (e >= n) return;
    const int s = edge_src(ei, e, is64);
    const int d = edge_dst(ei, e, is64);
    const float4* hp = (const float4*)(hs2 + (size_t)s * H2);
    float* o = agg2 + (size_t)d * H2;
    #pragma unroll
    for (int q = 0; q < 10; ++q) {
        float4 v = hp[q];
        atomicAdd(o + 4 * q + 0, v.x);
        atomicAdd(o + 4 * q + 1, v.y);
        atomicAdd(o + 4 * q + 2, v.z);
        atomicAdd(o + 4 * q + 3, v.w);
    }
}

// ---------------------------------------------------------------------------
// out[r][j] = log_softmax_j( dis[r]*(agg2[r][j] + hs2[r][j]) + b2[j] )
// Wave per row; in-place on d_out (agg2 == out).
__global__ __launch_bounds__(256) void epi2_kernel(
    float* __restrict__ out, const float* __restrict__ hs2,
    const float* __restrict__ b2, const float* __restrict__ dis, int n)
{
    const int lane = threadIdx.x & 63;
    const int row  = (blockIdx.x * blockDim.x + threadIdx.x) >> 6;
    if (row >= n) return;
    const float dv = dis[row];
    float val = 0.f, v = -INFINITY;
    if (lane < H2) {
        const float agg  = out[(size_t)row * H2 + lane];
        const float self = hs2[(size_t)row * H2 + lane];
        val = dv * (agg + self) + b2[lane];
        v = val;
    }
    #pragma unroll
    for (int off = 32; off > 0; off >>= 1) v = fmaxf(v, __shfl_xor(v, off, 64));
    float ex = (lane < H2) ? __expf(val - v) : 0.f;
    #pragma unroll
    for (int off = 32; off > 0; off >>= 1) ex += __shfl_xor(ex, off, 64);
    if (lane < H2) out[(size_t)row * H2 + lane] = val - v - logf(ex);
}

// ---------------------------------------------------------------------------
extern "C" void kernel_launch(void* const* d_in, const int* in_sizes, int n_in,
                              void* d_out, int out_size, void* d_ws, size_t ws_size,
                              hipStream_t stream)
{
    const float* x   = (const float*)d_in[0];
    const void*  ei  = d_in[1];                 // int32 or int64 [2, E] — detected
    const float* W1  = (const float*)d_in[2];
    const float* b1  = (const float*)d_in[3];
    const float* W2  = (const float*)d_in[4];
    const float* b2  = (const float*)d_in[5];
    float*       out = (float*)d_out;

    // workspace layout (floats); flag in first 16 floats keeps 64B alignment
    float* base = (float*)d_ws;
    int*   flag = (int*)base;                         // 1 int
    float* deg  = base + 16;                          // N
    float* dis  = deg  + N_NODES;                     // N
    float* hs1  = dis  + N_NODES;                     // N*16
    float* agg1 = hs1  + (size_t)N_NODES * H1;        // N*16
    float* hs2  = agg1 + (size_t)N_NODES * H1;        // N*40
    // total ~29.6 MB

    hipMemsetAsync(deg,  0, (size_t)N_NODES * sizeof(float), stream);
    hipMemsetAsync(agg1, 0, (size_t)N_NODES * H1 * sizeof(float), stream);
    hipMemsetAsync(out,  0, (size_t)N_NODES * H2 * sizeof(float), stream);

    detect_idx_kernel<<<1, 64, 0, stream>>>((const int*)ei, flag);

    const int EB = (N_EDGES + 255) / 256;
    count_deg_kernel<<<EB, 256, 0, stream>>>(ei, flag, deg, N_EDGES);
    gemm1_kernel<<<2048, 256, 0, stream>>>(x, W1, deg, hs1, dis, N_NODES);
    scatter1_kernel<<<EB, 256, 0, stream>>>(ei, flag, hs1, agg1, N_EDGES);
    l1fin_gemm2_kernel<<<(N_NODES + 255) / 256, 256, 0, stream>>>(agg1, hs1, b1, W2, dis, hs2, N_NODES);
    scatter2_kernel<<<EB, 256, 0, stream>>>(ei, flag, hs2, out, N_EDGES);
    epi2_kernel<<<(N_NODES * 64 + 255) / 256, 256, 0, stream>>>(out, hs2, b2, dis, N_NODES);
}

// Round 3
// 696.587 us; speedup vs baseline: 13.5202x; 13.5202x over previous
//
#include <hip/hip_runtime.h>
#include <math.h>

#define N_NODES 100000
#define N_EDGES 3200000
#define F_IN    512
#define H1      16
#define H2      40
#define SCAN_B  391   // ceil(N_NODES/256)

// ---------------------------------------------------------------------------
// Detect edge_index dtype: int64 (high int32 words all zero) vs int32.
__global__ void detect_idx_kernel(const int* __restrict__ ei, int* __restrict__ flag)
{
    if (threadIdx.x == 0 && blockIdx.x == 0) {
        int all_zero = 1;
        for (int i = 0; i < 64; ++i)
            if (ei[2 * i + 1] != 0) { all_zero = 0; break; }
        *flag = all_zero;  // 1 => int64 layout, 0 => int32 layout
    }
}

__device__ __forceinline__ int edge_src(const void* ei, int e, int is64)
{
    return is64 ? (int)((const long long*)ei)[e] : ((const int*)ei)[e];
}
__device__ __forceinline__ int edge_dst(const void* ei, int e, int is64)
{
    return is64 ? (int)((const long long*)ei)[N_EDGES + e]
                : ((const int*)ei)[N_EDGES + e];
}

// ---------------------------------------------------------------------------
__global__ __launch_bounds__(256) void count_deg_kernel(
    const void* __restrict__ ei, const int* __restrict__ flag,
    int* __restrict__ deg, int n)
{
    const int is64 = *flag;
    int e = blockIdx.x * blockDim.x + threadIdx.x;
    if (e >= n) return;
    atomicAdd(&deg[edge_dst(ei, e, is64)], 1);
}

// ---------------------------------------------------------------------------
// hs1[r][j] = (x[r] @ W1)[j] * dis[r];  dis[r] = rsqrt(deg[r]+1)
__global__ __launch_bounds__(256) void gemm1_kernel(
    const float* __restrict__ x, const float* __restrict__ W1,
    const int* __restrict__ deg, float* __restrict__ hs1,
    float* __restrict__ dis, int n)
{
    __shared__ float w[16][512];
    for (int idx = threadIdx.x; idx < F_IN * H1; idx += 256) {
        int k = idx >> 4, j = idx & 15;
        w[j][k] = W1[idx];
    }
    __syncthreads();

    const int lane = threadIdx.x & 63;
    const int wid  = (blockIdx.x * blockDim.x + threadIdx.x) >> 6;
    const int nw   = (gridDim.x * blockDim.x) >> 6;

    for (int r0 = wid * 2; r0 < n; r0 += nw * 2) {
        const int r1 = r0 + 1;
        const float* xa = x + (size_t)r0 * F_IN;
        const float* xb = x + (size_t)r1 * F_IN;
        float acca[16], accb[16];
        #pragma unroll
        for (int j = 0; j < 16; ++j) { acca[j] = 0.f; accb[j] = 0.f; }
        #pragma unroll
        for (int i = 0; i < 8; ++i) {
            const int k = lane + 64 * i;
            const float xva = xa[k];
            const float xvb = xb[k];
            #pragma unroll
            for (int j = 0; j < 16; ++j) {
                const float wv = w[j][k];
                acca[j] += xva * wv;
                accb[j] += xvb * wv;
            }
        }
        #pragma unroll
        for (int off = 32; off > 0; off >>= 1) {
            #pragma unroll
            for (int j = 0; j < 16; ++j) {
                acca[j] += __shfl_xor(acca[j], off, 64);
                accb[j] += __shfl_xor(accb[j], off, 64);
            }
        }
        const float da = rsqrtf((float)deg[r0] + 1.0f);
        const float db = rsqrtf((float)deg[r1] + 1.0f);
        if (lane == 0) { dis[r0] = da; dis[r1] = db; }
        if (lane < 16) {
            hs1[(size_t)r0 * H1 + lane] = acca[lane] * da;
            hs1[(size_t)r1 * H1 + lane] = accb[lane] * db;
        }
    }
}

// ---------------------------------------------------------------------------
// Exclusive scan of deg -> row_start (3 tiny kernels)
__global__ __launch_bounds__(256) void scanA_kernel(
    const int* __restrict__ deg, int* __restrict__ row_start,
    int* __restrict__ blocksum, int n)
{
    __shared__ int s[256];
    int i = blockIdx.x * 256 + threadIdx.x;
    int v = (i < n) ? deg[i] : 0;
    s[threadIdx.x] = v;
    __syncthreads();
    for (int off = 1; off < 256; off <<= 1) {
        int t = (threadIdx.x >= off) ? s[threadIdx.x - off] : 0;
        __syncthreads();
        s[threadIdx.x] += t;
        __syncthreads();
    }
    if (i < n) row_start[i] = s[threadIdx.x] - v;        // exclusive
    if (threadIdx.x == 255) blocksum[blockIdx.x] = s[255];
}

__global__ __launch_bounds__(512) void scanB_kernel(
    const int* __restrict__ blocksum, int* __restrict__ blockoff, int nb)
{
    __shared__ int s[512];
    int t = threadIdx.x;
    int v = (t < nb) ? blocksum[t] : 0;
    s[t] = v;
    __syncthreads();
    for (int off = 1; off < 512; off <<= 1) {
        int tv = (t >= off) ? s[t - off] : 0;
        __syncthreads();
        s[t] += tv;
        __syncthreads();
    }
    if (t < nb) blockoff[t] = s[t] - v;                  // exclusive
}

__global__ __launch_bounds__(256) void scanC_kernel(
    int* __restrict__ row_start, const int* __restrict__ blockoff, int n)
{
    int i = blockIdx.x * 256 + threadIdx.x;
    if (i < n) row_start[i] += blockoff[blockIdx.x];
}

// ---------------------------------------------------------------------------
// Destructive fill: row_start doubles as cursor. After this kernel,
// row_start[g] == end of node g's range; beg(g) = (g==0) ? 0 : row_start[g-1].
__global__ __launch_bounds__(256) void fill_csr_kernel(
    const void* __restrict__ ei, const int* __restrict__ flag,
    int* __restrict__ row_start, int* __restrict__ csr, int n)
{
    const int is64 = *flag;
    int e = blockIdx.x * blockDim.x + threadIdx.x;
    if (e >= n) return;
    const int s = edge_src(ei, e, is64);
    const int d = edge_dst(ei, e, is64);
    int pos = atomicAdd(&row_start[d], 1);
    csr[pos] = s;
}

// ---------------------------------------------------------------------------
// Pull aggregation over 16-dim rows: 4-lane group per node, float4 per lane.
// FUSE_L1: c = dis * relu(dis*(acc + hs1_self) + b1) (layer-1 epilogue)
template <int FUSE_L1>
__global__ __launch_bounds__(256) void pull16_kernel(
    const int* __restrict__ row_end, const int* __restrict__ csr,
    const float* __restrict__ rows, const float* __restrict__ dis,
    const float* __restrict__ b1, float* __restrict__ out, int n)
{
    int t = blockIdx.x * 256 + threadIdx.x;
    int g = t >> 2;
    int q = t & 3;
    if (g >= n) return;
    int beg = (g == 0) ? 0 : row_end[g - 1];
    int end = row_end[g];
    float4 acc = make_float4(0.f, 0.f, 0.f, 0.f);
    for (int i = beg; i < end; ++i) {
        int s = csr[i];
        float4 v = ((const float4*)(rows + (size_t)s * H1))[q];
        acc.x += v.x; acc.y += v.y; acc.z += v.z; acc.w += v.w;
    }
    if (FUSE_L1) {
        const float dv = dis[g];
        float4 h = ((const float4*)(rows + (size_t)g * H1))[q];  // self-loop
        float4 bq = ((const float4*)b1)[q];
        acc.x = dv * fmaxf(dv * (acc.x + h.x) + bq.x, 0.f);
        acc.y = dv * fmaxf(dv * (acc.y + h.y) + bq.y, 0.f);
        acc.z = dv * fmaxf(dv * (acc.z + h.z) + bq.z, 0.f);
        acc.w = dv * fmaxf(dv * (acc.w + h.w) + bq.w, 0.f);
    }
    ((float4*)(out + (size_t)g * H1))[q] = acc;
}

// ---------------------------------------------------------------------------
// out[r][j] = log_softmax_j( dis[r] * ((agg2[r]+c[r]) @ W2)[j] + b2[j] )
__global__ __launch_bounds__(256) void epi_kernel(
    const float* __restrict__ agg2, const float* __restrict__ c,
    const float* __restrict__ W2, const float* __restrict__ b2,
    const float* __restrict__ dis, float* __restrict__ out, int n)
{
    __shared__ float w[H1 * H2];
    for (int t = threadIdx.x; t < H1 * H2; t += 256) w[t] = W2[t];
    __syncthreads();

    const int row  = blockIdx.x * 4 + (threadIdx.x >> 6);
    if (row >= n) return;
    const int lane = threadIdx.x & 63;

    float tv = 0.f;
    if (lane < H1)
        tv = agg2[(size_t)row * H1 + lane] + c[(size_t)row * H1 + lane];

    const float dv = dis[row];
    float val = -INFINITY;
    if (lane < H2) {
        float s = 0.f;
        #pragma unroll
        for (int k = 0; k < H1; ++k) {
            float tk = __shfl(tv, k, 64);
            s += tk * w[k * H2 + lane];
        }
        val = dv * s + b2[lane];
    }
    float m = val;
    #pragma unroll
    for (int off = 32; off > 0; off >>= 1) m = fmaxf(m, __shfl_xor(m, off, 64));
    float ex = (lane < H2) ? __expf(val - m) : 0.f;
    #pragma unroll
    for (int off = 32; off > 0; off >>= 1) ex += __shfl_xor(ex, off, 64);
    if (lane < H2) out[(size_t)row * H2 + lane] = val - m - logf(ex);
}

// ---------------------------------------------------------------------------
extern "C" void kernel_launch(void* const* d_in, const int* in_sizes, int n_in,
                              void* d_out, int out_size, void* d_ws, size_t ws_size,
                              hipStream_t stream)
{
    const float* x   = (const float*)d_in[0];
    const void*  ei  = d_in[1];                 // int32 or int64 [2, E] — detected
    const float* W1  = (const float*)d_in[2];
    const float* b1  = (const float*)d_in[3];
    const float* W2  = (const float*)d_in[4];
    const float* b2  = (const float*)d_in[5];
    float*       out = (float*)d_out;

    // workspace layout (4-byte units); total ~27 MB
    int*   base      = (int*)d_ws;
    int*   flag      = base;                                   // [0,16)
    int*   deg       = base + 16;                              // N
    int*   row_start = deg + N_NODES;                          // N
    int*   blocksum  = row_start + N_NODES + 15;               // 512
    int*   blockoff  = blocksum + 512;                         // 512
    float* dis       = (float*)(blockoff + 512);               // N
    int*   csr       = (int*)(dis + N_NODES);                  // E
    float* hs1       = (float*)(csr + N_EDGES);                // N*16 (later agg2)
    float* c         = hs1 + (size_t)N_NODES * H1;             // N*16
    float* agg2      = hs1;                                    // alias: hs1 dead after pull1

    hipMemsetAsync(deg, 0, (size_t)N_NODES * sizeof(int), stream);

    detect_idx_kernel<<<1, 64, 0, stream>>>((const int*)ei, flag);

    const int EB = (N_EDGES + 255) / 256;
    count_deg_kernel<<<EB, 256, 0, stream>>>(ei, flag, deg, N_EDGES);
    gemm1_kernel<<<2048, 256, 0, stream>>>(x, W1, deg, hs1, dis, N_NODES);

    scanA_kernel<<<SCAN_B, 256, 0, stream>>>(deg, row_start, blocksum, N_NODES);
    scanB_kernel<<<1, 512, 0, stream>>>(blocksum, blockoff, SCAN_B);
    scanC_kernel<<<SCAN_B, 256, 0, stream>>>(row_start, blockoff, N_NODES);
    fill_csr_kernel<<<EB, 256, 0, stream>>>(ei, flag, row_start, csr, N_EDGES);

    const int PB = (N_NODES * 4 + 255) / 256;
    // pull1: aggregate hs1 -> fused layer-1 epilogue -> c
    pull16_kernel<1><<<PB, 256, 0, stream>>>(row_start, csr, hs1, dis, b1, c, N_NODES);
    // pull2: aggregate c -> agg2 (reuses hs1 buffer)
    pull16_kernel<0><<<PB, 256, 0, stream>>>(row_start, csr, c, dis, b1, agg2, N_NODES);

    epi_kernel<<<(N_NODES + 3) / 4, 256, 0, stream>>>(agg2, c, W2, b2, dis, out, N_NODES);
}

// Round 4
// 359.761 us; speedup vs baseline: 26.1786x; 1.9363x over previous
//
#include <hip/hip_runtime.h>
#include <math.h>

#define N_NODES 100000
#define N_EDGES 3200000
#define F_IN    512
#define H1      16
#define H2      40

#define NB      196      // coarse buckets: dst >> 9, 512 nodes each
#define BSH     9
#define BMASK   511
#define B1      512      // phase-1/2 blocks
#define EPB     6250     // edges per block (512*6250 = 3.2M exactly)

// ---------------------------------------------------------------------------
// Detect edge_index dtype: int64 (high int32 words all zero) vs int32.
__global__ void detect_idx_kernel(const int* __restrict__ ei, int* __restrict__ flag)
{
    if (threadIdx.x == 0 && blockIdx.x == 0) {
        int all_zero = 1;
        for (int i = 0; i < 64; ++i)
            if (ei[2 * i + 1] != 0) { all_zero = 0; break; }
        *flag = all_zero;  // 1 => int64 layout, 0 => int32 layout
    }
}

__device__ __forceinline__ int edge_src(const void* ei, int e, int is64)
{
    return is64 ? (int)((const long long*)ei)[e] : ((const int*)ei)[e];
}
__device__ __forceinline__ int edge_dst(const void* ei, int e, int is64)
{
    return is64 ? (int)((const long long*)ei)[N_EDGES + e]
                : ((const int*)ei)[N_EDGES + e];
}

// ---------------------------------------------------------------------------
// Phase 1: per-block coarse-bucket histogram (LDS atomics only).
__global__ __launch_bounds__(256) void hist_kernel(
    const void* __restrict__ ei, const int* __restrict__ flag,
    int* __restrict__ cntoff)
{
    __shared__ int h[NB];
    if (threadIdx.x < NB) h[threadIdx.x] = 0;
    __syncthreads();
    const int is64 = *flag;
    const int e0 = blockIdx.x * EPB;
    for (int i = threadIdx.x; i < EPB; i += 256) {
        int e = e0 + i;
        if (e < N_EDGES) atomicAdd(&h[edge_dst(ei, e, is64) >> BSH], 1);
    }
    __syncthreads();
    if (threadIdx.x < NB) cntoff[blockIdx.x * NB + threadIdx.x] = h[threadIdx.x];
}

// ---------------------------------------------------------------------------
// Phase 1b: per-bucket exclusive scan over the 512 blocks (one wave/bucket).
// In-place: cntoff[i][b] becomes the within-bucket offset of block i's run.
// bstart[b] receives the bucket's total count (scanned by scanb_kernel).
__global__ __launch_bounds__(256) void scanblk_kernel(
    int* __restrict__ cntoff, int* __restrict__ bstart)
{
    const int lane   = threadIdx.x & 63;
    const int bucket = blockIdx.x * 4 + (threadIdx.x >> 6);
    if (bucket >= NB) return;
    int run = 0;
    #pragma unroll
    for (int c = 0; c < B1 / 64; ++c) {
        const int i = c * 64 + lane;
        const int v = cntoff[i * NB + bucket];
        int s = v;
        #pragma unroll
        for (int off = 1; off < 64; off <<= 1) {
            int t = __shfl_up(s, off, 64);
            if (lane >= off) s += t;
        }
        cntoff[i * NB + bucket] = run + (s - v);   // exclusive within bucket
        run += __shfl(s, 63, 64);
    }
    if (lane == 0) bstart[bucket] = run;
}

// Phase 1c: exclusive scan of the 196 bucket totals.
__global__ __launch_bounds__(256) void scanb_kernel(int* __restrict__ bstart)
{
    __shared__ int s[256];
    const int t = threadIdx.x;
    const int v = (t < NB) ? bstart[t] : 0;
    s[t] = v;
    __syncthreads();
    for (int off = 1; off < 256; off <<= 1) {
        int tv = (t >= off) ? s[t - off] : 0;
        __syncthreads();
        s[t] += tv;
        __syncthreads();
    }
    if (t < NB) bstart[t] = s[t] - v;              // exclusive
    if (t == NB - 1) bstart[NB] = s[t];            // total == N_EDGES
}

// ---------------------------------------------------------------------------
// Phase 2: scatter edges into bucket-sorted packed array (LDS cursors only).
// packed = (src << 9) | (dst & 511); src < 2^17 so it fits an int.
__global__ __launch_bounds__(256) void scatter_bucket_kernel(
    const void* __restrict__ ei, const int* __restrict__ flag,
    const int* __restrict__ cntoff, const int* __restrict__ bstart,
    int* __restrict__ packed)
{
    __shared__ int cur[NB];
    if (threadIdx.x < NB)
        cur[threadIdx.x] = cntoff[blockIdx.x * NB + threadIdx.x] + bstart[threadIdx.x];
    __syncthreads();
    const int is64 = *flag;
    const int e0 = blockIdx.x * EPB;
    for (int i = threadIdx.x; i < EPB; i += 256) {
        int e = e0 + i;
        if (e >= N_EDGES) break;
        const int s = edge_src(ei, e, is64);
        const int d = edge_dst(ei, e, is64);
        const int b = d >> BSH;
        const int pos = atomicAdd(&cur[b], 1);
        packed[pos] = (s << BSH) | (d & BMASK);
    }
}

// ---------------------------------------------------------------------------
// Phase 3: one block per bucket; fine CSR via LDS histogram+scan+scatter.
// Writes deg[], row_end[] (inclusive prefix; beg(g)=row_end[g-1]), csr[].
__global__ __launch_bounds__(512) void bucket_csr_kernel(
    const int* __restrict__ packed, const int* __restrict__ bstart,
    int* __restrict__ deg, int* __restrict__ row_end, int* __restrict__ csr)
{
    __shared__ int hist[512];
    __shared__ int off2[512];
    __shared__ int stmp[256];
    const int b    = blockIdx.x;
    const int tid  = threadIdx.x;
    const int base = bstart[b];
    const int m    = bstart[b + 1] - base;

    hist[tid] = 0;
    __syncthreads();
    for (int i = tid; i < m; i += 512)
        atomicAdd(&hist[packed[base + i] & BMASK], 1);
    __syncthreads();

    int h0 = 0, h1 = 0;
    if (tid < 256) {
        h0 = hist[2 * tid];
        h1 = hist[2 * tid + 1];
        stmp[tid] = h0 + h1;
    }
    __syncthreads();
    for (int off = 1; off < 256; off <<= 1) {
        int t = 0;
        if (tid < 256 && tid >= off) t = stmp[tid - off];
        __syncthreads();
        if (tid < 256) stmp[tid] += t;
        __syncthreads();
    }
    if (tid < 256) {
        const int ex2 = stmp[tid] - (h0 + h1);     // exclusive over pairs
        off2[2 * tid]     = ex2;
        off2[2 * tid + 1] = ex2 + h0;
        const int g0 = (b << BSH) + 2 * tid;
        const int g1 = g0 + 1;
        if (g0 < N_NODES) { deg[g0] = h0; row_end[g0] = base + ex2 + h0; }
        if (g1 < N_NODES) { deg[g1] = h1; row_end[g1] = base + ex2 + h0 + h1; }
    }
    __syncthreads();
    for (int i = tid; i < m; i += 512) {
        const int p = packed[base + i];
        const int pos = atomicAdd(&off2[p & BMASK], 1);
        csr[base + pos] = p >> BSH;
    }
}

// ---------------------------------------------------------------------------
// hs1[r][j] = (x[r] @ W1)[j] * dis[r];  dis[r] = rsqrt(deg[r]+1)
__global__ __launch_bounds__(256) void gemm1_kernel(
    const float* __restrict__ x, const float* __restrict__ W1,
    const int* __restrict__ deg, float* __restrict__ hs1,
    float* __restrict__ dis, int n)
{
    __shared__ float w[16][512];
    for (int idx = threadIdx.x; idx < F_IN * H1; idx += 256) {
        int k = idx >> 4, j = idx & 15;
        w[j][k] = W1[idx];
    }
    __syncthreads();

    const int lane = threadIdx.x & 63;
    const int wid  = (blockIdx.x * blockDim.x + threadIdx.x) >> 6;
    const int nw   = (gridDim.x * blockDim.x) >> 6;

    for (int r0 = wid * 2; r0 < n; r0 += nw * 2) {
        const int r1 = r0 + 1;
        const float* xa = x + (size_t)r0 * F_IN;
        const float* xb = x + (size_t)r1 * F_IN;
        float acca[16], accb[16];
        #pragma unroll
        for (int j = 0; j < 16; ++j) { acca[j] = 0.f; accb[j] = 0.f; }
        #pragma unroll
        for (int i = 0; i < 8; ++i) {
            const int k = lane + 64 * i;
            const float xva = xa[k];
            const float xvb = xb[k];
            #pragma unroll
            for (int j = 0; j < 16; ++j) {
                const float wv = w[j][k];
                acca[j] += xva * wv;
                accb[j] += xvb * wv;
            }
        }
        #pragma unroll
        for (int off = 32; off > 0; off >>= 1) {
            #pragma unroll
            for (int j = 0; j < 16; ++j) {
                acca[j] += __shfl_xor(acca[j], off, 64);
                accb[j] += __shfl_xor(accb[j], off, 64);
            }
        }
        const float da = rsqrtf((float)deg[r0] + 1.0f);
        const float db = rsqrtf((float)deg[r1] + 1.0f);
        if (lane == 0) { dis[r0] = da; dis[r1] = db; }
        if (lane < 16) {
            hs1[(size_t)r0 * H1 + lane] = acca[lane] * da;
            hs1[(size_t)r1 * H1 + lane] = accb[lane] * db;
        }
    }
}

// ---------------------------------------------------------------------------
// Pull aggregation over 16-dim rows: 4-lane group per node, float4 per lane.
// FUSE_L1: c = dis * relu(dis*(acc + hs1_self) + b1) (layer-1 epilogue)
template <int FUSE_L1>
__global__ __launch_bounds__(256) void pull16_kernel(
    const int* __restrict__ row_end, const int* __restrict__ csr,
    const float* __restrict__ rows, const float* __restrict__ dis,
    const float* __restrict__ b1, float* __restrict__ out, int n)
{
    int t = blockIdx.x * 256 + threadIdx.x;
    int g = t >> 2;
    int q = t & 3;
    if (g >= n) return;
    int beg = (g == 0) ? 0 : row_end[g - 1];
    int end = row_end[g];
    float4 acc = make_float4(0.f, 0.f, 0.f, 0.f);
    for (int i = beg; i < end; ++i) {
        int s = csr[i];
        float4 v = ((const float4*)(rows + (size_t)s * H1))[q];
        acc.x += v.x; acc.y += v.y; acc.z += v.z; acc.w += v.w;
    }
    if (FUSE_L1) {
        const float dv = dis[g];
        float4 h = ((const float4*)(rows + (size_t)g * H1))[q];  // self-loop
        float4 bq = ((const float4*)b1)[q];
        acc.x = dv * fmaxf(dv * (acc.x + h.x) + bq.x, 0.f);
        acc.y = dv * fmaxf(dv * (acc.y + h.y) + bq.y, 0.f);
        acc.z = dv * fmaxf(dv * (acc.z + h.z) + bq.z, 0.f);
        acc.w = dv * fmaxf(dv * (acc.w + h.w) + bq.w, 0.f);
    }
    ((float4*)(out + (size_t)g * H1))[q] = acc;
}

// ---------------------------------------------------------------------------
// out[r][j] = log_softmax_j( dis[r] * ((agg2[r]+c[r]) @ W2)[j] + b2[j] )
__global__ __launch_bounds__(256) void epi_kernel(
    const float* __restrict__ agg2, const float* __restrict__ c,
    const float* __restrict__ W2, const float* __restrict__ b2,
    const float* __restrict__ dis, float* __restrict__ out, int n)
{
    __shared__ float w[H1 * H2];
    for (int t = threadIdx.x; t < H1 * H2; t += 256) w[t] = W2[t];
    __syncthreads();

    const int row  = blockIdx.x * 4 + (threadIdx.x >> 6);
    if (row >= n) return;
    const int lane = threadIdx.x & 63;

    float tv = 0.f;
    if (lane < H1)
        tv = agg2[(size_t)row * H1 + lane] + c[(size_t)row * H1 + lane];

    const float dv = dis[row];
    float val = -INFINITY;
    if (lane < H2) {
        float s = 0.f;
        #pragma unroll
        for (int k = 0; k < H1; ++k) {
            float tk = __shfl(tv, k, 64);
            s += tk * w[k * H2 + lane];
        }
        val = dv * s + b2[lane];
    }
    float m = val;
    #pragma unroll
    for (int off = 32; off > 0; off >>= 1) m = fmaxf(m, __shfl_xor(m, off, 64));
    float ex = (lane < H2) ? __expf(val - m) : 0.f;
    #pragma unroll
    for (int off = 32; off > 0; off >>= 1) ex += __shfl_xor(ex, off, 64);
    if (lane < H2) out[(size_t)row * H2 + lane] = val - m - logf(ex);
}

// ---------------------------------------------------------------------------
extern "C" void kernel_launch(void* const* d_in, const int* in_sizes, int n_in,
                              void* d_out, int out_size, void* d_ws, size_t ws_size,
                              hipStream_t stream)
{
    const float* x   = (const float*)d_in[0];
    const void*  ei  = d_in[1];                 // int32 or int64 [2, E] — detected
    const float* W1  = (const float*)d_in[2];
    const float* b1  = (const float*)d_in[3];
    const float* W2  = (const float*)d_in[4];
    const float* b2  = (const float*)d_in[5];
    float*       out = (float*)d_out;

    // workspace layout (4-byte units); ~27.2 MB total, all float4-aligned
    int*   base    = (int*)d_ws;
    int*   flag    = base;                                  // 16
    int*   deg     = base + 16;                             // N
    int*   row_end = deg + N_NODES;                         // N
    int*   bstart  = row_end + N_NODES;                     // 256 (197 used)
    int*   cntoff  = bstart + 256;                          // B1*NB = 100352
    float* dis     = (float*)(cntoff + B1 * NB);            // N
    int*   csr     = (int*)(dis + N_NODES);                 // E
    int*   packed  = csr + N_EDGES;                         // E (dead after phase 3)
    float* hs1     = (float*)packed;                        // alias: N*16
    float* c       = hs1 + (size_t)N_NODES * H1;            // alias: N*16
    float* agg2    = hs1;                                   // hs1 dead after pull1

    detect_idx_kernel<<<1, 64, 0, stream>>>((const int*)ei, flag);

    hist_kernel<<<B1, 256, 0, stream>>>(ei, flag, cntoff);
    scanblk_kernel<<<(NB + 3) / 4, 256, 0, stream>>>(cntoff, bstart);
    scanb_kernel<<<1, 256, 0, stream>>>(bstart);
    scatter_bucket_kernel<<<B1, 256, 0, stream>>>(ei, flag, cntoff, bstart, packed);
    bucket_csr_kernel<<<NB, 512, 0, stream>>>(packed, bstart, deg, row_end, csr);

    gemm1_kernel<<<2048, 256, 0, stream>>>(x, W1, deg, hs1, dis, N_NODES);

    const int PB = (N_NODES * 4 + 255) / 256;
    pull16_kernel<1><<<PB, 256, 0, stream>>>(row_end, csr, hs1, dis, b1, c, N_NODES);
    pull16_kernel<0><<<PB, 256, 0, stream>>>(row_end, csr, c, dis, b1, agg2, N_NODES);

    epi_kernel<<<(N_NODES + 3) / 4, 256, 0, stream>>>(agg2, c, W2, b2, dis, out, N_NODES);
}

// Round 5
// 306.511 us; speedup vs baseline: 30.7265x; 1.1737x over previous
//
#include <hip/hip_runtime.h>
#include <math.h>

#define N_NODES 100000
#define N_EDGES 3200000
#define F_IN    512
#define H1      16
#define H2      40

#define NB      196      // coarse buckets: dst >> 9, 512 nodes each
#define BSH     9
#define BMASK   511
#define B1      512      // phase-1/2 blocks
#define EPB     6250     // edges per block (512*6250 = 3.2M exactly)

// ---------------------------------------------------------------------------
// Detect edge_index dtype: int64 (high int32 words all zero) vs int32.
__global__ void detect_idx_kernel(const int* __restrict__ ei, int* __restrict__ flag)
{
    if (threadIdx.x == 0 && blockIdx.x == 0) {
        int all_zero = 1;
        for (int i = 0; i < 64; ++i)
            if (ei[2 * i + 1] != 0) { all_zero = 0; break; }
        *flag = all_zero;  // 1 => int64 layout, 0 => int32 layout
    }
}

__device__ __forceinline__ int edge_src(const void* ei, int e, int is64)
{
    return is64 ? (int)((const long long*)ei)[e] : ((const int*)ei)[e];
}
__device__ __forceinline__ int edge_dst(const void* ei, int e, int is64)
{
    return is64 ? (int)((const long long*)ei)[N_EDGES + e]
                : ((const int*)ei)[N_EDGES + e];
}

// ---------------------------------------------------------------------------
// Phase 1: per-block coarse-bucket histogram (LDS atomics only).
__global__ __launch_bounds__(256) void hist_kernel(
    const void* __restrict__ ei, const int* __restrict__ flag,
    int* __restrict__ cntoff)
{
    __shared__ int h[NB];
    if (threadIdx.x < NB) h[threadIdx.x] = 0;
    __syncthreads();
    const int is64 = *flag;
    const int e0 = blockIdx.x * EPB;
    for (int i = threadIdx.x; i < EPB; i += 256) {
        int e = e0 + i;
        if (e < N_EDGES) atomicAdd(&h[edge_dst(ei, e, is64) >> BSH], 1);
    }
    __syncthreads();
    if (threadIdx.x < NB) cntoff[blockIdx.x * NB + threadIdx.x] = h[threadIdx.x];
}

// ---------------------------------------------------------------------------
// Phase 1b: per-bucket exclusive scan over the 512 blocks (one wave/bucket).
__global__ __launch_bounds__(256) void scanblk_kernel(
    int* __restrict__ cntoff, int* __restrict__ bstart)
{
    const int lane   = threadIdx.x & 63;
    const int bucket = blockIdx.x * 4 + (threadIdx.x >> 6);
    if (bucket >= NB) return;
    int run = 0;
    #pragma unroll
    for (int c = 0; c < B1 / 64; ++c) {
        const int i = c * 64 + lane;
        const int v = cntoff[i * NB + bucket];
        int s = v;
        #pragma unroll
        for (int off = 1; off < 64; off <<= 1) {
            int t = __shfl_up(s, off, 64);
            if (lane >= off) s += t;
        }
        cntoff[i * NB + bucket] = run + (s - v);   // exclusive within bucket
        run += __shfl(s, 63, 64);
    }
    if (lane == 0) bstart[bucket] = run;
}

// Phase 1c: exclusive scan of the 196 bucket totals.
__global__ __launch_bounds__(256) void scanb_kernel(int* __restrict__ bstart)
{
    __shared__ int s[256];
    const int t = threadIdx.x;
    const int v = (t < NB) ? bstart[t] : 0;
    s[t] = v;
    __syncthreads();
    for (int off = 1; off < 256; off <<= 1) {
        int tv = (t >= off) ? s[t - off] : 0;
        __syncthreads();
        s[t] += tv;
        __syncthreads();
    }
    if (t < NB) bstart[t] = s[t] - v;              // exclusive
    if (t == NB - 1) bstart[NB] = s[t];            // total == N_EDGES
}

// ---------------------------------------------------------------------------
// Phase 2: scatter edges into bucket-sorted packed array (LDS cursors only).
__global__ __launch_bounds__(256) void scatter_bucket_kernel(
    const void* __restrict__ ei, const int* __restrict__ flag,
    const int* __restrict__ cntoff, const int* __restrict__ bstart,
    int* __restrict__ packed)
{
    __shared__ int cur[NB];
    if (threadIdx.x < NB)
        cur[threadIdx.x] = cntoff[blockIdx.x * NB + threadIdx.x] + bstart[threadIdx.x];
    __syncthreads();
    const int is64 = *flag;
    const int e0 = blockIdx.x * EPB;
    for (int i = threadIdx.x; i < EPB; i += 256) {
        int e = e0 + i;
        if (e >= N_EDGES) break;
        const int s = edge_src(ei, e, is64);
        const int d = edge_dst(ei, e, is64);
        const int b = d >> BSH;
        const int pos = atomicAdd(&cur[b], 1);
        packed[pos] = (s << BSH) | (d & BMASK);
    }
}

// ---------------------------------------------------------------------------
// Phase 3: one block per bucket; fine CSR via LDS histogram+scan+scatter.
__global__ __launch_bounds__(512) void bucket_csr_kernel(
    const int* __restrict__ packed, const int* __restrict__ bstart,
    int* __restrict__ deg, int* __restrict__ row_end, int* __restrict__ csr)
{
    __shared__ int hist[512];
    __shared__ int off2[512];
    __shared__ int stmp[256];
    const int b    = blockIdx.x;
    const int tid  = threadIdx.x;
    const int base = bstart[b];
    const int m    = bstart[b + 1] - base;

    hist[tid] = 0;
    __syncthreads();
    for (int i = tid; i < m; i += 512)
        atomicAdd(&hist[packed[base + i] & BMASK], 1);
    __syncthreads();

    int h0 = 0, h1 = 0;
    if (tid < 256) {
        h0 = hist[2 * tid];
        h1 = hist[2 * tid + 1];
        stmp[tid] = h0 + h1;
    }
    __syncthreads();
    for (int off = 1; off < 256; off <<= 1) {
        int t = 0;
        if (tid < 256 && tid >= off) t = stmp[tid - off];
        __syncthreads();
        if (tid < 256) stmp[tid] += t;
        __syncthreads();
    }
    if (tid < 256) {
        const int ex2 = stmp[tid] - (h0 + h1);     // exclusive over pairs
        off2[2 * tid]     = ex2;
        off2[2 * tid + 1] = ex2 + h0;
        const int g0 = (b << BSH) + 2 * tid;
        const int g1 = g0 + 1;
        if (g0 < N_NODES) { deg[g0] = h0; row_end[g0] = base + ex2 + h0; }
        if (g1 < N_NODES) { deg[g1] = h1; row_end[g1] = base + ex2 + h0 + h1; }
    }
    __syncthreads();
    for (int i = tid; i < m; i += 512) {
        const int p = packed[base + i];
        const int pos = atomicAdd(&off2[p & BMASK], 1);
        csr[base + pos] = p >> BSH;
    }
}

// ---------------------------------------------------------------------------
// hs1[r][j] = (x[r] @ W1)[j] * dis[r];  dis[r] = rsqrt(deg[r]+1)
// Thread per row; W1 in LDS read at wave-uniform addresses (broadcast);
// acc[16] in registers; no cross-lane ops at all.
__global__ __launch_bounds__(256) void gemm1_kernel(
    const float* __restrict__ x, const float* __restrict__ W1,
    const int* __restrict__ deg, float* __restrict__ hs1,
    float* __restrict__ dis, int n)
{
    __shared__ float w[F_IN * H1];                 // [512][16] row-major, 32 KB
    for (int idx = threadIdx.x; idx < F_IN * H1; idx += 256)
        w[idx] = W1[idx];
    __syncthreads();

    const int r = blockIdx.x * 256 + threadIdx.x;
    if (r >= n) return;

    const float4* xr = (const float4*)(x + (size_t)r * F_IN);
    float acc[H1];
    #pragma unroll
    for (int j = 0; j < H1; ++j) acc[j] = 0.f;

    for (int k4 = 0; k4 < F_IN / 4; ++k4) {
        const float4 xv = xr[k4];
        const float* wk = w + k4 * 4 * H1;         // wave-uniform address
        #pragma unroll
        for (int j = 0; j < H1; ++j)
            acc[j] += xv.x * wk[j] + xv.y * wk[H1 + j]
                    + xv.z * wk[2 * H1 + j] + xv.w * wk[3 * H1 + j];
    }

    const float dv = rsqrtf((float)deg[r] + 1.0f);
    dis[r] = dv;
    float4* o = (float4*)(hs1 + (size_t)r * H1);
    #pragma unroll
    for (int q = 0; q < 4; ++q) {
        float4 v;
        v.x = acc[4 * q + 0] * dv;
        v.y = acc[4 * q + 1] * dv;
        v.z = acc[4 * q + 2] * dv;
        v.w = acc[4 * q + 3] * dv;
        o[q] = v;
    }
}

// ---------------------------------------------------------------------------
// Pull aggregation over 16-dim rows: 4-lane group per node, float4 per lane.
// FUSE_L1: c = dis * relu(dis*(acc + hs1_self) + b1) (layer-1 epilogue)
template <int FUSE_L1>
__global__ __launch_bounds__(256) void pull16_kernel(
    const int* __restrict__ row_end, const int* __restrict__ csr,
    const float* __restrict__ rows, const float* __restrict__ dis,
    const float* __restrict__ b1, float* __restrict__ out, int n)
{
    int t = blockIdx.x * 256 + threadIdx.x;
    int g = t >> 2;
    int q = t & 3;
    if (g >= n) return;
    int beg = (g == 0) ? 0 : row_end[g - 1];
    int end = row_end[g];
    float4 acc = make_float4(0.f, 0.f, 0.f, 0.f);
    for (int i = beg; i < end; ++i) {
        int s = csr[i];
        float4 v = ((const float4*)(rows + (size_t)s * H1))[q];
        acc.x += v.x; acc.y += v.y; acc.z += v.z; acc.w += v.w;
    }
    if (FUSE_L1) {
        const float dv = dis[g];
        float4 h = ((const float4*)(rows + (size_t)g * H1))[q];  // self-loop
        float4 bq = ((const float4*)b1)[q];
        acc.x = dv * fmaxf(dv * (acc.x + h.x) + bq.x, 0.f);
        acc.y = dv * fmaxf(dv * (acc.y + h.y) + bq.y, 0.f);
        acc.z = dv * fmaxf(dv * (acc.z + h.z) + bq.z, 0.f);
        acc.w = dv * fmaxf(dv * (acc.w + h.w) + bq.w, 0.f);
    }
    ((float4*)(out + (size_t)g * H1))[q] = acc;
}

// ---------------------------------------------------------------------------
// out[r][j] = log_softmax_j( dis[r] * ((agg2[r]+c[r]) @ W2)[j] + b2[j] )
__global__ __launch_bounds__(256) void epi_kernel(
    const float* __restrict__ agg2, const float* __restrict__ c,
    const float* __restrict__ W2, const float* __restrict__ b2,
    const float* __restrict__ dis, float* __restrict__ out, int n)
{
    __shared__ float w[H1 * H2];
    for (int t = threadIdx.x; t < H1 * H2; t += 256) w[t] = W2[t];
    __syncthreads();

    const int row  = blockIdx.x * 4 + (threadIdx.x >> 6);
    if (row >= n) return;
    const int lane = threadIdx.x & 63;

    float tv = 0.f;
    if (lane < H1)
        tv = agg2[(size_t)row * H1 + lane] + c[(size_t)row * H1 + lane];

    const float dv = dis[row];
    float val = -INFINITY;
    if (lane < H2) {
        float s = 0.f;
        #pragma unroll
        for (int k = 0; k < H1; ++k) {
            float tk = __shfl(tv, k, 64);
            s += tk * w[k * H2 + lane];
        }
        val = dv * s + b2[lane];
    }
    float m = val;
    #pragma unroll
    for (int off = 32; off > 0; off >>= 1) m = fmaxf(m, __shfl_xor(m, off, 64));
    float ex = (lane < H2) ? __expf(val - m) : 0.f;
    #pragma unroll
    for (int off = 32; off > 0; off >>= 1) ex += __shfl_xor(ex, off, 64);
    if (lane < H2) out[(size_t)row * H2 + lane] = val - m - logf(ex);
}

// ---------------------------------------------------------------------------
extern "C" void kernel_launch(void* const* d_in, const int* in_sizes, int n_in,
                              void* d_out, int out_size, void* d_ws, size_t ws_size,
                              hipStream_t stream)
{
    const float* x   = (const float*)d_in[0];
    const void*  ei  = d_in[1];                 // int32 or int64 [2, E] — detected
    const float* W1  = (const float*)d_in[2];
    const float* b1  = (const float*)d_in[3];
    const float* W2  = (const float*)d_in[4];
    const float* b2  = (const float*)d_in[5];
    float*       out = (float*)d_out;

    // workspace layout (4-byte units); ~27.2 MB total, all float4-aligned
    int*   base    = (int*)d_ws;
    int*   flag    = base;                                  // 16
    int*   deg     = base + 16;                             // N
    int*   row_end = deg + N_NODES;                         // N
    int*   bstart  = row_end + N_NODES;                     // 256 (197 used)
    int*   cntoff  = bstart + 256;                          // B1*NB = 100352
    float* dis     = (float*)(cntoff + B1 * NB);            // N
    int*   csr     = (int*)(dis + N_NODES);                 // E
    int*   packed  = csr + N_EDGES;                         // E (dead after phase 3)
    float* hs1     = (float*)packed;                        // alias: N*16
    float* c       = hs1 + (size_t)N_NODES * H1;            // alias: N*16
    float* agg2    = hs1;                                   // hs1 dead after pull1

    detect_idx_kernel<<<1, 64, 0, stream>>>((const int*)ei, flag);

    hist_kernel<<<B1, 256, 0, stream>>>(ei, flag, cntoff);
    scanblk_kernel<<<(NB + 3) / 4, 256, 0, stream>>>(cntoff, bstart);
    scanb_kernel<<<1, 256, 0, stream>>>(bstart);
    scatter_bucket_kernel<<<B1, 256, 0, stream>>>(ei, flag, cntoff, bstart, packed);
    bucket_csr_kernel<<<NB, 512, 0, stream>>>(packed, bstart, deg, row_end, csr);

    gemm1_kernel<<<(N_NODES + 255) / 256, 256, 0, stream>>>(x, W1, deg, hs1, dis, N_NODES);

    const int PB = (N_NODES * 4 + 255) / 256;
    pull16_kernel<1><<<PB, 256, 0, stream>>>(row_end, csr, hs1, dis, b1, c, N_NODES);
    pull16_kernel<0><<<PB, 256, 0, stream>>>(row_end, csr, c, dis, b1, agg2, N_NODES);

    epi_kernel<<<(N_NODES + 3) / 4, 256, 0, stream>>>(agg2, c, W2, b2, dis, out, N_NODES);
}

// Round 6
// 296.072 us; speedup vs baseline: 31.8098x; 1.0353x over previous
//
#include <hip/hip_runtime.h>
#include <math.h>

#define N_NODES 100000
#define N_EDGES 3200000
#define F_IN    512
#define H1      16
#define H2      40

#define NB      196      // coarse buckets: dst >> 9, 512 nodes each
#define BSH     9
#define BMASK   511
#define B1      512      // phase-1/2 blocks
#define EPB     6250     // edges per block (512*6250 = 3.2M exactly)

// ---------------------------------------------------------------------------
// Detect edge_index dtype: int64 (high int32 words all zero) vs int32.
__global__ void detect_idx_kernel(const int* __restrict__ ei, int* __restrict__ flag)
{
    if (threadIdx.x == 0 && blockIdx.x == 0) {
        int all_zero = 1;
        for (int i = 0; i < 64; ++i)
            if (ei[2 * i + 1] != 0) { all_zero = 0; break; }
        *flag = all_zero;  // 1 => int64 layout, 0 => int32 layout
    }
}

__device__ __forceinline__ int edge_src(const void* ei, int e, int is64)
{
    return is64 ? (int)((const long long*)ei)[e] : ((const int*)ei)[e];
}
__device__ __forceinline__ int edge_dst(const void* ei, int e, int is64)
{
    return is64 ? (int)((const long long*)ei)[N_EDGES + e]
                : ((const int*)ei)[N_EDGES + e];
}

// ---------------------------------------------------------------------------
// Phase 1: per-block coarse-bucket histogram (LDS atomics only).
__global__ __launch_bounds__(256) void hist_kernel(
    const void* __restrict__ ei, const int* __restrict__ flag,
    int* __restrict__ cntoff)
{
    __shared__ int h[NB];
    if (threadIdx.x < NB) h[threadIdx.x] = 0;
    __syncthreads();
    const int is64 = *flag;
    const int e0 = blockIdx.x * EPB;
    for (int i = threadIdx.x; i < EPB; i += 256) {
        int e = e0 + i;
        if (e < N_EDGES) atomicAdd(&h[edge_dst(ei, e, is64) >> BSH], 1);
    }
    __syncthreads();
    if (threadIdx.x < NB) cntoff[blockIdx.x * NB + threadIdx.x] = h[threadIdx.x];
}

// ---------------------------------------------------------------------------
// Phase 1b: per-bucket exclusive scan over the 512 blocks (one wave/bucket).
__global__ __launch_bounds__(256) void scanblk_kernel(
    int* __restrict__ cntoff, int* __restrict__ bstart)
{
    const int lane   = threadIdx.x & 63;
    const int bucket = blockIdx.x * 4 + (threadIdx.x >> 6);
    if (bucket >= NB) return;
    int run = 0;
    #pragma unroll
    for (int c = 0; c < B1 / 64; ++c) {
        const int i = c * 64 + lane;
        const int v = cntoff[i * NB + bucket];
        int s = v;
        #pragma unroll
        for (int off = 1; off < 64; off <<= 1) {
            int t = __shfl_up(s, off, 64);
            if (lane >= off) s += t;
        }
        cntoff[i * NB + bucket] = run + (s - v);   // exclusive within bucket
        run += __shfl(s, 63, 64);
    }
    if (lane == 0) bstart[bucket] = run;
}

// Phase 1c: exclusive scan of the 196 bucket totals.
__global__ __launch_bounds__(256) void scanb_kernel(int* __restrict__ bstart)
{
    __shared__ int s[256];
    const int t = threadIdx.x;
    const int v = (t < NB) ? bstart[t] : 0;
    s[t] = v;
    __syncthreads();
    for (int off = 1; off < 256; off <<= 1) {
        int tv = (t >= off) ? s[t - off] : 0;
        __syncthreads();
        s[t] += tv;
        __syncthreads();
    }
    if (t < NB) bstart[t] = s[t] - v;              // exclusive
    if (t == NB - 1) bstart[NB] = s[t];            // total == N_EDGES
}

// ---------------------------------------------------------------------------
// Phase 2: scatter edges into bucket-sorted packed array (LDS cursors only).
__global__ __launch_bounds__(256) void scatter_bucket_kernel(
    const void* __restrict__ ei, const int* __restrict__ flag,
    const int* __restrict__ cntoff, const int* __restrict__ bstart,
    int* __restrict__ packed)
{
    __shared__ int cur[NB];
    if (threadIdx.x < NB)
        cur[threadIdx.x] = cntoff[blockIdx.x * NB + threadIdx.x] + bstart[threadIdx.x];
    __syncthreads();
    const int is64 = *flag;
    const int e0 = blockIdx.x * EPB;
    for (int i = threadIdx.x; i < EPB; i += 256) {
        int e = e0 + i;
        if (e >= N_EDGES) break;
        const int s = edge_src(ei, e, is64);
        const int d = edge_dst(ei, e, is64);
        const int b = d >> BSH;
        const int pos = atomicAdd(&cur[b], 1);
        packed[pos] = (s << BSH) | (d & BMASK);
    }
}

// ---------------------------------------------------------------------------
// Phase 3: one block per bucket; fine CSR via LDS histogram+scan+scatter.
__global__ __launch_bounds__(512) void bucket_csr_kernel(
    const int* __restrict__ packed, const int* __restrict__ bstart,
    int* __restrict__ deg, int* __restrict__ row_end, int* __restrict__ csr)
{
    __shared__ int hist[512];
    __shared__ int off2[512];
    __shared__ int stmp[256];
    const int b    = blockIdx.x;
    const int tid  = threadIdx.x;
    const int base = bstart[b];
    const int m    = bstart[b + 1] - base;

    hist[tid] = 0;
    __syncthreads();
    for (int i = tid; i < m; i += 512)
        atomicAdd(&hist[packed[base + i] & BMASK], 1);
    __syncthreads();

    int h0 = 0, h1 = 0;
    if (tid < 256) {
        h0 = hist[2 * tid];
        h1 = hist[2 * tid + 1];
        stmp[tid] = h0 + h1;
    }
    __syncthreads();
    for (int off = 1; off < 256; off <<= 1) {
        int t = 0;
        if (tid < 256 && tid >= off) t = stmp[tid - off];
        __syncthreads();
        if (tid < 256) stmp[tid] += t;
        __syncthreads();
    }
    if (tid < 256) {
        const int ex2 = stmp[tid] - (h0 + h1);     // exclusive over pairs
        off2[2 * tid]     = ex2;
        off2[2 * tid + 1] = ex2 + h0;
        const int g0 = (b << BSH) + 2 * tid;
        const int g1 = g0 + 1;
        if (g0 < N_NODES) { deg[g0] = h0; row_end[g0] = base + ex2 + h0; }
        if (g1 < N_NODES) { deg[g1] = h1; row_end[g1] = base + ex2 + h0 + h1; }
    }
    __syncthreads();
    for (int i = tid; i < m; i += 512) {
        const int p = packed[base + i];
        const int pos = atomicAdd(&off2[p & BMASK], 1);
        csr[base + pos] = p >> BSH;
    }
}

// ---------------------------------------------------------------------------
// hs1[r][j] = (x[r] @ W1)[j] * dis[r];  dis[r] = rsqrt(deg[r]+1)
// Thread per row. W1 read DIRECTLY from global at wave-uniform addresses:
// uniformity analysis scalarizes these to s_load + v_fma-with-SGPR-operand
// (LDS is the wrong home for uniform data: uniform ds_read broadcasts only
// 16 useful B/instr and serialized on the CU's single LDS pipe — the ~60 µs
// we just paid). W1 is 32 KB, K$/L1-resident.
__global__ __launch_bounds__(256) void gemm1_kernel(
    const float* __restrict__ x, const float* __restrict__ W1,
    const int* __restrict__ deg, float* __restrict__ hs1,
    float* __restrict__ dis, int n)
{
    const int r = blockIdx.x * 256 + threadIdx.x;
    if (r >= n) return;

    const float4* xr = (const float4*)(x + (size_t)r * F_IN);
    float acc[H1];
    #pragma unroll
    for (int j = 0; j < H1; ++j) acc[j] = 0.f;

    #pragma unroll 2
    for (int k4 = 0; k4 < F_IN / 4; ++k4) {
        const float4 xv = xr[k4];
        const float* wk = W1 + k4 * 4 * H1;        // wave-uniform address
        #pragma unroll
        for (int j = 0; j < H1; ++j)
            acc[j] += xv.x * wk[j] + xv.y * wk[H1 + j]
                    + xv.z * wk[2 * H1 + j] + xv.w * wk[3 * H1 + j];
    }

    const float dv = rsqrtf((float)deg[r] + 1.0f);
    dis[r] = dv;
    float4* o = (float4*)(hs1 + (size_t)r * H1);
    #pragma unroll
    for (int q = 0; q < 4; ++q) {
        float4 v;
        v.x = acc[4 * q + 0] * dv;
        v.y = acc[4 * q + 1] * dv;
        v.z = acc[4 * q + 2] * dv;
        v.w = acc[4 * q + 3] * dv;
        o[q] = v;
    }
}

// ---------------------------------------------------------------------------
// Pull aggregation over 16-dim rows: 4-lane group per node, float4 per lane.
// FUSE_L1: c = dis * relu(dis*(acc + hs1_self) + b1) (layer-1 epilogue)
template <int FUSE_L1>
__global__ __launch_bounds__(256) void pull16_kernel(
    const int* __restrict__ row_end, const int* __restrict__ csr,
    const float* __restrict__ rows, const float* __restrict__ dis,
    const float* __restrict__ b1, float* __restrict__ out, int n)
{
    int t = blockIdx.x * 256 + threadIdx.x;
    int g = t >> 2;
    int q = t & 3;
    if (g >= n) return;
    int beg = (g == 0) ? 0 : row_end[g - 1];
    int end = row_end[g];
    float4 acc = make_float4(0.f, 0.f, 0.f, 0.f);
    for (int i = beg; i < end; ++i) {
        int s = csr[i];
        float4 v = ((const float4*)(rows + (size_t)s * H1))[q];
        acc.x += v.x; acc.y += v.y; acc.z += v.z; acc.w += v.w;
    }
    if (FUSE_L1) {
        const float dv = dis[g];
        float4 h = ((const float4*)(rows + (size_t)g * H1))[q];  // self-loop
        float4 bq = ((const float4*)b1)[q];
        acc.x = dv * fmaxf(dv * (acc.x + h.x) + bq.x, 0.f);
        acc.y = dv * fmaxf(dv * (acc.y + h.y) + bq.y, 0.f);
        acc.z = dv * fmaxf(dv * (acc.z + h.z) + bq.z, 0.f);
        acc.w = dv * fmaxf(dv * (acc.w + h.w) + bq.w, 0.f);
    }
    ((float4*)(out + (size_t)g * H1))[q] = acc;
}

// ---------------------------------------------------------------------------
// out[r][j] = log_softmax_j( dis[r] * ((agg2[r]+c[r]) @ W2)[j] + b2[j] )
__global__ __launch_bounds__(256) void epi_kernel(
    const float* __restrict__ agg2, const float* __restrict__ c,
    const float* __restrict__ W2, const float* __restrict__ b2,
    const float* __restrict__ dis, float* __restrict__ out, int n)
{
    __shared__ float w[H1 * H2];
    for (int t = threadIdx.x; t < H1 * H2; t += 256) w[t] = W2[t];
    __syncthreads();

    const int row  = blockIdx.x * 4 + (threadIdx.x >> 6);
    if (row >= n) return;
    const int lane = threadIdx.x & 63;

    float tv = 0.f;
    if (lane < H1)
        tv = agg2[(size_t)row * H1 + lane] + c[(size_t)row * H1 + lane];

    const float dv = dis[row];
    float val = -INFINITY;
    if (lane < H2) {
        float s = 0.f;
        #pragma unroll
        for (int k = 0; k < H1; ++k) {
            float tk = __shfl(tv, k, 64);
            s += tk * w[k * H2 + lane];
        }
        val = dv * s + b2[lane];
    }
    float m = val;
    #pragma unroll
    for (int off = 32; off > 0; off >>= 1) m = fmaxf(m, __shfl_xor(m, off, 64));
    float ex = (lane < H2) ? __expf(val - m) : 0.f;
    #pragma unroll
    for (int off = 32; off > 0; off >>= 1) ex += __shfl_xor(ex, off, 64);
    if (lane < H2) out[(size_t)row * H2 + lane] = val - m - logf(ex);
}

// ---------------------------------------------------------------------------
extern "C" void kernel_launch(void* const* d_in, const int* in_sizes, int n_in,
                              void* d_out, int out_size, void* d_ws, size_t ws_size,
                              hipStream_t stream)
{
    const float* x   = (const float*)d_in[0];
    const void*  ei  = d_in[1];                 // int32 or int64 [2, E] — detected
    const float* W1  = (const float*)d_in[2];
    const float* b1  = (const float*)d_in[3];
    const float* W2  = (const float*)d_in[4];
    const float* b2  = (const float*)d_in[5];
    float*       out = (float*)d_out;

    // workspace layout (4-byte units); ~27.2 MB total, all float4-aligned
    int*   base    = (int*)d_ws;
    int*   flag    = base;                                  // 16
    int*   deg     = base + 16;                             // N
    int*   row_end = deg + N_NODES;                         // N
    int*   bstart  = row_end + N_NODES;                     // 256 (197 used)
    int*   cntoff  = bstart + 256;                          // B1*NB = 100352
    float* dis     = (float*)(cntoff + B1 * NB);            // N
    int*   csr     = (int*)(dis + N_NODES);                 // E
    int*   packed  = csr + N_EDGES;                         // E (dead after phase 3)
    float* hs1     = (float*)packed;                        // alias: N*16
    float* c       = hs1 + (size_t)N_NODES * H1;            // alias: N*16
    float* agg2    = hs1;                                   // hs1 dead after pull1

    detect_idx_kernel<<<1, 64, 0, stream>>>((const int*)ei, flag);

    hist_kernel<<<B1, 256, 0, stream>>>(ei, flag, cntoff);
    scanblk_kernel<<<(NB + 3) / 4, 256, 0, stream>>>(cntoff, bstart);
    scanb_kernel<<<1, 256, 0, stream>>>(bstart);
    scatter_bucket_kernel<<<B1, 256, 0, stream>>>(ei, flag, cntoff, bstart, packed);
    bucket_csr_kernel<<<NB, 512, 0, stream>>>(packed, bstart, deg, row_end, csr);

    gemm1_kernel<<<(N_NODES + 255) / 256, 256, 0, stream>>>(x, W1, deg, hs1, dis, N_NODES);

    const int PB = (N_NODES * 4 + 255) / 256;
    pull16_kernel<1><<<PB, 256, 0, stream>>>(row_end, csr, hs1, dis, b1, c, N_NODES);
    pull16_kernel<0><<<PB, 256, 0, stream>>>(row_end, csr, c, dis, b1, agg2, N_NODES);

    epi_kernel<<<(N_NODES + 3) / 4, 256, 0, stream>>>(agg2, c, W2, b2, dis, out, N_NODES);
}